// Round 14
// baseline (977.453 us; speedup 1.0000x reference)
//
#include <hip/hip_runtime.h>

// Vanilla tanh RNN. B=64, T=2048, I=64, H=128, fp32.
//   xw[b,t,h] = sum_i x[b,t,i]*W[h,i] + b_ih[h] + b_hh[h]
//   h_t = tanh(xw_t + h_{t-1} @ U^T);  outputs: ys [B,T,H], h_last [B,H]
//
// R19. Post-mortem R17 (scan 557us, VGPR=40, conflicts 512):
//  lgkm barrier = real but small (-11us). Decisive numbers: skeleton
//  (R12 probe, no fma/reduce) = 347 cyc/step; full scan = 653; VALU
//  floor = ~250. 347+250 ~= 653: the DS/barrier skeleton and VALU work
//  SERIALIZE — lockstep waves all stall on the same chain, nothing
//  overlaps. Fix needs independent work per barrier round, and the RNN
//  has it free: the batch dim (U is batch-shared).
// This round: 2 BATCHES PER BLOCK (32 blocks, 512 thr, launch_bounds
// (512,1) -> 2 waves/SIMD, VGPR cap 256). Per round: both batches'
// 8 b128 reads issue together; batch-1 FMA hides batch-0 DS latency;
// skeleton amortized over 2 steps. Round ~ max(skel ~400, VALU ~500)
// -> ~250-300 cyc/batch-step (was 653). CH 32->16 (LDS 34.5 KB:
// xbuf/obuf 8KB x2 batches + hb 2.5KB). Core per-batch math unchanged
// from proven R12/R17 (20j skew, 3-stage DPP butterfly, xv pipeline,
// lgkm-only barriers).
// gemm: same latency signature (104us vs ~25 floor, no barriers) ->
// explicit next-row prefetch breaks the ds_read->fma serial chain.

#define RNN_B 64
#define RNN_T 2048
#define RNN_I 64
#define RNN_H 128
#define CH    16            // timesteps per staged chunk (2-batch LDS fit)
#define NCH   (RNN_T / CH)  // 128 chunks

__device__ __forceinline__ float fast_tanh(float x) {
  // tanh(x) = 1 - 2/(e^{2x}+1);  e^{2x} = exp2(x * 2*log2(e))
  float e = __builtin_amdgcn_exp2f(x * 2.885390081777927f);
  return 1.0f - 2.0f * __builtin_amdgcn_rcpf(e + 1.0f);
}

template <int CTRL>
__device__ __forceinline__ float dpp_add(float s) {
  int o = __builtin_amdgcn_mov_dpp(__float_as_int(s), CTRL, 0xF, 0xF, true);
  return s + __int_as_float(o);
}

__device__ __forceinline__ void fma4(float4& a, const float4 u, const float4 h) {
  a.x = fmaf(u.x, h.x, a.x);
  a.y = fmaf(u.y, h.y, a.y);
  a.z = fmaf(u.z, h.z, a.z);
  a.w = fmaf(u.w, h.w, a.w);
}

__device__ __forceinline__ float hsum(const float4 a) {
  return (a.x + a.y) + (a.z + a.w);
}

// Workgroup barrier WITHOUT the vmcnt(0) drain __syncthreads implies.
// Steps touch only LDS; outstanding global prefetch/flush may float across.
__device__ __forceinline__ void barrier_lgkm() {
  asm volatile("s_waitcnt lgkmcnt(0)\n\ts_barrier" ::: "memory");
}

// ---------------------------------------------------------------------------
// Kernel 1: xw = x @ W^T + (b_ih + b_hh).  M=B*T=131072, N=128, K=64.
// 2048 blocks x 256 threads, 64 x-rows/block, 2 blocks/CU.
// thread -> (g=tid>>2: rows 2g,2g+1; q=tid&3: cols [16q,16q+16)):
// 8 float4 of W in regs. NEW: next row's x-slice prefetched into regs
// before the current row's FMA chain (breaks ds_read->use serial chain;
// the kernel sat at ~104us vs ~25us issue floor = exposed LDS latency).
// Quad butterfly (xor1+xor2); lanes q<2 store row 2g+q.
// ---------------------------------------------------------------------------
__global__ __launch_bounds__(256, 2) void rnn_xw_gemm(
    const float* __restrict__ x, const float* __restrict__ W,
    const float* __restrict__ b_ih, const float* __restrict__ b_hh,
    float* __restrict__ xw) {
  const int tid = threadIdx.x;
  const int g   = tid >> 2;   // 0..63 : rows 2g, 2g+1
  const int q   = tid & 3;    // col slice [16q, 16q+16)

  // W tile: rows 2g,2g+1, cols [16q,16q+16) -> 8 float4 (32 VGPRs)
  float4 w[2][4];
#pragma unroll
  for (int r = 0; r < 2; ++r) {
    const float4* Wr = (const float4*)(W + (2 * g + r) * RNN_I + 16 * q);
#pragma unroll
    for (int m = 0; m < 4; ++m) w[r][m] = Wr[m];
  }
  const int row_own = 2 * g + (q & 1);
  const float bias  = b_ih[row_own] + b_hh[row_own];

  // Stage 64 rows of x (64x64 fp32 = 16 KB) into LDS, coalesced.
  __shared__ __align__(16) float4 xs[64 * 16];
  const long rbase = (long)blockIdx.x * 64;
  const float4* xg = (const float4*)(x + rbase * RNN_I);
#pragma unroll
  for (int jj = 0; jj < 4; ++jj) xs[tid + 256 * jj] = xg[tid + 256 * jj];
  __syncthreads();

  // Software pipeline: row r+1's reads issue before row r's FMA chain.
  const float4* xr0 = xs + q * 4;
  float4 n0 = xr0[0], n1 = xr0[1], n2 = xr0[2], n3 = xr0[3];
#pragma unroll 4
  for (int r = 0; r < 64; ++r) {
    const float4 hv0 = n0, hv1 = n1, hv2 = n2, hv3 = n3;
    const float4* xn = xs + ((r + 1) & 63) * 16 + q * 4;  // wraps harmlessly
    n0 = xn[0]; n1 = xn[1]; n2 = xn[2]; n3 = xn[3];
    float4 a0 = {0, 0, 0, 0}, a1 = {0, 0, 0, 0};
    fma4(a0, w[0][0], hv0); fma4(a0, w[0][1], hv1);
    fma4(a0, w[0][2], hv2); fma4(a0, w[0][3], hv3);
    fma4(a1, w[1][0], hv0); fma4(a1, w[1][1], hv1);
    fma4(a1, w[1][2], hv2); fma4(a1, w[1][3], hv3);
    float s0 = hsum(a0), s1 = hsum(a1);
    s0 = dpp_add<0xB1>(s0); s0 = dpp_add<0x4E>(s0);
    s1 = dpp_add<0xB1>(s1); s1 = dpp_add<0x4E>(s1);
    const float own = (q & 1) ? s1 : s0;
    if (q < 2)
      xw[(rbase + r) * RNN_H + row_own] = own + bias;
  }
}

// ---------------------------------------------------------------------------
// Kernel 2: sequential scan, TWO batches per block. 32 blocks, 512 thr
// (8 waves, 2/SIMD at 1 block/CU). thread(g=tid>>3, j=tid&7) owns U rows
// {2g,2g+1} x cols [16j,16j+16) (32 VGPR) shared by both batches.
// Per round: 8 b128 reads (both batches) issue together; 16 fma4;
// 2x 3-stage DPP butterfly; 2x tanh; writes; ONE lgkm barrier ->
// skeleton amortized over 2 batch-steps, chains overlap.
// ---------------------------------------------------------------------------
__global__ __launch_bounds__(512, 1) void rnn_scan(
    const float* xw,            // aliases `out` — no __restrict__
    float* out, float* __restrict__ hlast,
    const float* __restrict__ h0, const float* __restrict__ U) {
  const int bp  = blockIdx.x;      // batch pair: handles 2*bp, 2*bp+1
  const int tid = threadIdx.x;     // 0..511
  const int g   = tid >> 3;        // 0..63 : rows 2g, 2g+1
  const int j   = tid & 7;         // k-slice [16j, 16j+16)
  const int r_own = 2 * g + (j & 1);

  __shared__ __align__(16) float hb0[2][160];        // ping 0: [batch][skewed]
  __shared__ __align__(16) float hb1[2][160];        // ping 1
  __shared__ __align__(16) float xbuf[2][CH * RNN_H];  // 8 KB per batch
  __shared__ __align__(16) float obuf[2][CH * RNN_H];  // 8 KB per batch

  // U tile: rows 2g,2g+1, cols [16j,16j+16) -> 8 float4 (32 VGPRs)
  float4 u[2][4];
#pragma unroll
  for (int r = 0; r < 2; ++r) {
    const float4* Ur = (const float4*)(U + (2 * g + r) * RNN_H + 16 * j);
#pragma unroll
    for (int m = 0; m < 4; ++m) u[r][m] = Ur[m];
  }

  if (tid < RNN_H) {
    hb0[0][(tid >> 4) * 20 + (tid & 15)] = h0[(2 * bp) * RNN_H + tid];
  } else if (tid < 2 * RNN_H) {
    const int t = tid - RNN_H;
    hb0[1][(t >> 4) * 20 + (t & 15)] = h0[(2 * bp + 1) * RNN_H + t];
  }

  const int hoff = (r_own >> 4) * 20 + (r_own & 15);  // skewed h slot
  const long base0   = (long)(2 * bp) * RNN_T * RNN_H;
  const long base1   = (long)(2 * bp + 1) * RNN_T * RNN_H;
  const float4* xw40 = (const float4*)(xw + base0);
  const float4* xw41 = (const float4*)(xw + base1);
  float4* out40      = (float4*)(out + base0);
  float4* out41      = (float4*)(out + base1);
  float4* xb40       = (float4*)xbuf[0];
  float4* xb41       = (float4*)xbuf[1];
  const float4* ob40 = (const float4*)obuf[0];
  const float4* ob41 = (const float4*)obuf[1];

  // Prologue: prefetch chunk 0 (CH*128 = 512 float4/batch, 1/thread).
  float4 p0 = xw40[tid], p1 = xw41[tid];

  float xv0, xv1;  // current step's xw values (pipelined one step ahead)

  auto step = [&](const float* sA, const float* sB, float* dA, float* dB,
                  int tc) {
    // Issue ALL 8 reads first — batch B's loads overlap batch A's chain.
    const float4* hpA = (const float4*)(sA + 20 * j);
    const float4* hpB = (const float4*)(sB + 20 * j);
    const float4 A0 = hpA[0], A1 = hpA[1], A2 = hpA[2], A3 = hpA[3];
    const float4 B0 = hpB[0], B1 = hpB[1], B2 = hpB[2], B3 = hpB[3];
    float4 a0 = {0,0,0,0}, a1 = {0,0,0,0};   // batch A rows 2g, 2g+1
    float4 c0 = {0,0,0,0}, c1 = {0,0,0,0};   // batch B rows 2g, 2g+1
    fma4(a0, u[0][0], A0); fma4(a0, u[0][1], A1);
    fma4(a0, u[0][2], A2); fma4(a0, u[0][3], A3);
    fma4(a1, u[1][0], A0); fma4(a1, u[1][1], A1);
    fma4(a1, u[1][2], A2); fma4(a1, u[1][3], A3);
    fma4(c0, u[0][0], B0); fma4(c0, u[0][1], B1);
    fma4(c0, u[0][2], B2); fma4(c0, u[0][3], B3);
    fma4(c1, u[1][0], B0); fma4(c1, u[1][1], B1);
    fma4(c1, u[1][2], B2); fma4(c1, u[1][3], B3);
    // Pre-barrier read of NEXT step's xv (xbuf stable within the chunk).
    const float xn0 = xbuf[0][((tc + 1) & (CH - 1)) * RNN_H + r_own];
    const float xn1 = xbuf[1][((tc + 1) & (CH - 1)) * RNN_H + r_own];
    float sa0 = hsum(a0), sa1 = hsum(a1), sc0 = hsum(c0), sc1 = hsum(c1);
    sa0 = dpp_add<0xB1>(sa0); sa0 = dpp_add<0x4E>(sa0); sa0 = dpp_add<0x141>(sa0);
    sa1 = dpp_add<0xB1>(sa1); sa1 = dpp_add<0x4E>(sa1); sa1 = dpp_add<0x141>(sa1);
    sc0 = dpp_add<0xB1>(sc0); sc0 = dpp_add<0x4E>(sc0); sc0 = dpp_add<0x141>(sc0);
    sc1 = dpp_add<0xB1>(sc1); sc1 = dpp_add<0x4E>(sc1); sc1 = dpp_add<0x141>(sc1);
    const float ownA = (j & 1) ? sa1 : sa0;
    const float ownB = (j & 1) ? sc1 : sc0;
    const float vA = fast_tanh(ownA + xv0);
    const float vB = fast_tanh(ownB + xv1);
    if (j < 2) {
      dA[hoff] = vA;                        // ds_write: next h, batch A
      dB[hoff] = vB;                        // ds_write: next h, batch B
    } else if ((j & 6) == 4) {              // j == 4,5
      obuf[0][tc * RNN_H + r_own] = vA;
      obuf[1][tc * RNN_H + r_own] = vB;
    }
    barrier_lgkm();
    xv0 = xn0; xv1 = xn1;
  };

  for (int c = 0; c < NCH; ++c) {
    // Phase A: commit prefetched chunk; issue next prefetch; flush c-1.
    xb40[tid] = p0; xb41[tid] = p1;
    if (c + 1 < NCH) {
      p0 = xw40[(long)(c + 1) * 512 + tid];
      p1 = xw41[(long)(c + 1) * 512 + tid];
    }
    if (c > 0) {
      out40[(long)(c - 1) * 512 + tid] = ob40[tid];
      out41[(long)(c - 1) * 512 + tid] = ob41[tid];
    }
    barrier_lgkm();

    // Phase B: 16 steps x 2 batches, LDS-only, compile-time ping-pong.
    xv0 = xbuf[0][r_own]; xv1 = xbuf[1][r_own];
    for (int tc = 0; tc < CH; tc += 2) {
      step(hb0[0], hb0[1], hb1[0], hb1[1], tc);
      step(hb1[0], hb1[1], hb0[0], hb0[1], tc + 1);
    }
  }

  // Final chunk flush + h_last (last step's barrier makes data visible)
  out40[(long)(NCH - 1) * 512 + tid] = ob40[tid];
  out41[(long)(NCH - 1) * 512 + tid] = ob41[tid];
  if (tid < RNN_H) {
    hlast[(2 * bp) * RNN_H + tid] = hb0[0][(tid >> 4) * 20 + (tid & 15)];
  } else if (tid < 2 * RNN_H) {
    const int t = tid - RNN_H;
    hlast[(2 * bp + 1) * RNN_H + t] = hb0[1][(t >> 4) * 20 + (t & 15)];
  }
}

extern "C" void kernel_launch(void* const* d_in, const int* in_sizes, int n_in,
                              void* d_out, int out_size, void* d_ws, size_t ws_size,
                              hipStream_t stream) {
  const float* x    = (const float*)d_in[0];
  const float* h0   = (const float*)d_in[1];
  const float* W    = (const float*)d_in[2];
  const float* U    = (const float*)d_in[3];
  const float* b_ih = (const float*)d_in[4];
  const float* b_hh = (const float*)d_in[5];

  float* out   = (float*)d_out;                           // [B,T,H]
  float* hlast = out + (long)RNN_B * RNN_T * RNN_H;       // [B,H]

  // Stage 1: xw into the output region (read-before-write in scan, per chunk)
  rnn_xw_gemm<<<(RNN_B * RNN_T) / 64, 256, 0, stream>>>(x, W, b_ih, b_hh, out);
  // Stage 2: sequential recurrence, 2 batch elements per block
  rnn_scan<<<RNN_B / 2, 512, 0, stream>>>(out, out, hlast, h0, U);
}

// Round 16
// 694.416 us; speedup vs baseline: 1.4076x; 1.4076x over previous
//
#include <hip/hip_runtime.h>

// Vanilla tanh RNN. B=64, T=2048, I=64, H=128, fp32.
//   xw[b,t,h] = sum_i x[b,t,i]*W[h,i] + b_ih[h] + b_hh[h]
//   h_t = tanh(xw_t + h_{t-1} @ U^T);  outputs: ys [B,T,H], h_last [B,H]
//
// R21 = R20 with the cluster-asm spelled per SCALAR component.
// R20's "+v"(float4) failed to compile: gfx950 inline asm can't tie
// vector-typed operands ("tied indirect register inputs"). pin4 (R8)
// compiled because it constrained scalars. Mechanism unchanged:
// one empty asm consuming all load results forces the 4 ds_read_b128
// to issue back-to-back with ONE lgkm wait and all results co-live.
//
// Context (R20 theory, unmeasured): R17's VGPR=40 = u(32)+prefetch(8)
// exactly -> the 4 hv float4s are never simultaneously live -> 4 SERIAL
// LDS latencies per step (~150-250 of 653 cyc/step). The allocator has
// refused co-live loads 4 times (R6/R8/R16/R19); this forces it.
// Everything else byte-identical to R17 (proven 557us: lgkm barriers,
// 20j skew, 3-stage DPP butterfly, xv pipeline, obuf staging).

#define RNN_B 64
#define RNN_T 2048
#define RNN_I 64
#define RNN_H 128
#define CH    32            // timesteps per staged chunk
#define NCH   (RNN_T / CH)  // 64 chunks

__device__ __forceinline__ float fast_tanh(float x) {
  // tanh(x) = 1 - 2/(e^{2x}+1);  e^{2x} = exp2(x * 2*log2(e))
  float e = __builtin_amdgcn_exp2f(x * 2.885390081777927f);
  return 1.0f - 2.0f * __builtin_amdgcn_rcpf(e + 1.0f);
}

template <int CTRL>
__device__ __forceinline__ float dpp_add(float s) {
  int o = __builtin_amdgcn_mov_dpp(__float_as_int(s), CTRL, 0xF, 0xF, true);
  return s + __int_as_float(o);
}

__device__ __forceinline__ void fma4(float4& a, const float4 u, const float4 h) {
  a.x = fmaf(u.x, h.x, a.x);
  a.y = fmaf(u.y, h.y, a.y);
  a.z = fmaf(u.z, h.z, a.z);
  a.w = fmaf(u.w, h.w, a.w);
}

__device__ __forceinline__ float hsum(const float4 a) {
  return (a.x + a.y) + (a.z + a.w);
}

// Force 4 loaded float4s to be co-live at one point (scalar "+v" ties —
// vector ties don't compile on gfx950).
__device__ __forceinline__ void cluster4(float4& a, float4& b, float4& c,
                                         float4& d) {
  asm volatile("" : "+v"(a.x), "+v"(a.y), "+v"(a.z), "+v"(a.w),
                    "+v"(b.x), "+v"(b.y), "+v"(b.z), "+v"(b.w),
                    "+v"(c.x), "+v"(c.y), "+v"(c.z), "+v"(c.w),
                    "+v"(d.x), "+v"(d.y), "+v"(d.z), "+v"(d.w));
}

// Workgroup barrier WITHOUT the vmcnt(0) drain __syncthreads implies.
// Steps touch only LDS; outstanding global prefetch/flush may float across.
__device__ __forceinline__ void barrier_lgkm() {
  asm volatile("s_waitcnt lgkmcnt(0)\n\ts_barrier" ::: "memory");
}

// ---------------------------------------------------------------------------
// Kernel 1: xw = x @ W^T + (b_ih + b_hh).  M=B*T=131072, N=128, K=64.
// 2048 blocks x 256 threads, 64 x-rows/block, 2 blocks/CU.
// thread -> (g=tid>>2: rows 2g,2g+1; q=tid&3: cols [16q,16q+16)):
// 8 float4 of W in regs. Per row: 4 ds_read_b128 CLUSTERED via the
// empty-asm consumption point -> one LDS latency instead of 4.
// Quad butterfly (xor1+xor2); lanes q<2 store row 2g+q (coalesced).
// ---------------------------------------------------------------------------
__global__ __launch_bounds__(256, 2) void rnn_xw_gemm(
    const float* __restrict__ x, const float* __restrict__ W,
    const float* __restrict__ b_ih, const float* __restrict__ b_hh,
    float* __restrict__ xw) {
  const int tid = threadIdx.x;
  const int g   = tid >> 2;   // 0..63 : rows 2g, 2g+1
  const int q   = tid & 3;    // col slice [16q, 16q+16)

  // W tile: rows 2g,2g+1, cols [16q,16q+16) -> 8 float4 (32 VGPRs)
  float4 w[2][4];
#pragma unroll
  for (int r = 0; r < 2; ++r) {
    const float4* Wr = (const float4*)(W + (2 * g + r) * RNN_I + 16 * q);
#pragma unroll
    for (int m = 0; m < 4; ++m) w[r][m] = Wr[m];
  }
  const int row_own = 2 * g + (q & 1);
  const float bias  = b_ih[row_own] + b_hh[row_own];

  // Stage 64 rows of x (64x64 fp32 = 16 KB) into LDS, coalesced.
  __shared__ __align__(16) float4 xs[64 * 16];
  const long rbase = (long)blockIdx.x * 64;
  const float4* xg = (const float4*)(x + rbase * RNN_I);
#pragma unroll
  for (int jj = 0; jj < 4; ++jj) xs[tid + 256 * jj] = xg[tid + 256 * jj];
  __syncthreads();

#pragma unroll 4
  for (int r = 0; r < 64; ++r) {
    const float4* xr = xs + r * 16 + q * 4;
    float4 hv0 = xr[0], hv1 = xr[1], hv2 = xr[2], hv3 = xr[3];
    // Cluster: all 4 reads issued, waited once, results live together.
    cluster4(hv0, hv1, hv2, hv3);
    float4 a0 = {0, 0, 0, 0}, a1 = {0, 0, 0, 0};
    fma4(a0, w[0][0], hv0); fma4(a0, w[0][1], hv1);
    fma4(a0, w[0][2], hv2); fma4(a0, w[0][3], hv3);
    fma4(a1, w[1][0], hv0); fma4(a1, w[1][1], hv1);
    fma4(a1, w[1][2], hv2); fma4(a1, w[1][3], hv3);
    float s0 = hsum(a0), s1 = hsum(a1);
    s0 = dpp_add<0xB1>(s0); s0 = dpp_add<0x4E>(s0);
    s1 = dpp_add<0xB1>(s1); s1 = dpp_add<0x4E>(s1);
    const float own = (q & 1) ? s1 : s0;
    if (q < 2)
      xw[(rbase + r) * RNN_H + row_own] = own + bias;
  }
}

// ---------------------------------------------------------------------------
// Kernel 2: sequential scan. 1 block/batch, 512 threads (8 waves, 2/SIMD).
// == R17's proven core (557us, VGPR=40, conflicts 512) + read clustering.
// thread(g=tid>>3: rows 2g,2g+1; j=tid&7: cols [16j,16j+16)):
// 8 float4 of U in regs. 4x ds_read_b128/step (20j skew, conflict-free)
// issued AS A CLUSTER with the xv read -> 1 LDS latency on the chain,
// not 4-5. 3-stage DPP butterfly {0xB1,0x4E,0x141}; j<2 writes next-h,
// j==4,5 writes obuf. lgkm-only barriers (proven R17).
// ---------------------------------------------------------------------------
__global__ __launch_bounds__(512, 2) void rnn_scan(
    const float* xw,            // aliases `out` — no __restrict__
    float* out, float* __restrict__ hlast,
    const float* __restrict__ h0, const float* __restrict__ U) {
  const int b     = blockIdx.x;
  const int tid   = threadIdx.x;  // 0..511
  const int g     = tid >> 3;     // 0..63 : rows 2g, 2g+1
  const int j     = tid & 7;      // k-slice [16j, 16j+16)
  const int r_own = 2 * g + (j & 1);

  __shared__ __align__(16) float hbuf0[8 * 20];     // skewed h state
  __shared__ __align__(16) float hbuf1[8 * 20];
  __shared__ __align__(16) float xbuf[CH * RNN_H];  // 16 KB
  __shared__ __align__(16) float obuf[CH * RNN_H];  // 16 KB

  // U tile: rows 2g,2g+1, cols [16j,16j+16) -> 8 float4 (32 VGPRs)
  float4 u[2][4];
#pragma unroll
  for (int r = 0; r < 2; ++r) {
    const float4* Ur = (const float4*)(U + (2 * g + r) * RNN_H + 16 * j);
#pragma unroll
    for (int m = 0; m < 4; ++m) u[r][m] = Ur[m];
  }

  if (tid < RNN_H)
    hbuf0[(tid >> 4) * 20 + (tid & 15)] = h0[b * RNN_H + tid];

  const int hoff = (r_own >> 4) * 20 + (r_own & 15);  // skewed write slot
  const long base   = (long)b * RNN_T * RNN_H;
  const float4* xw4 = (const float4*)(xw + base);
  float4* out4      = (float4*)(out + base);
  float4* xb4       = (float4*)xbuf;
  const float4* ob4 = (const float4*)obuf;

  // Prologue: prefetch chunk 0 into regs (2 float4/thread).
  float4 p0 = xw4[tid], p1 = xw4[tid + 512];

  float xv_cur;  // xw value for the CURRENT step, read one step ahead

  auto step = [&](const float* src, float* dst, int tc) {
    const float4* hp = (const float4*)(src + 20 * j);
    float4 hv0 = hp[0], hv1 = hp[1], hv2 = hp[2], hv3 = hp[3];
    float xv_next = xbuf[((tc + 1) & (CH - 1)) * RNN_H + r_own];
    // Cluster: 5 DS reads issued back-to-back, ONE lgkm wait, all
    // results live simultaneously (forces the allocator's hand).
    asm volatile("" : "+v"(hv0.x), "+v"(hv0.y), "+v"(hv0.z), "+v"(hv0.w),
                      "+v"(hv1.x), "+v"(hv1.y), "+v"(hv1.z), "+v"(hv1.w),
                      "+v"(hv2.x), "+v"(hv2.y), "+v"(hv2.z), "+v"(hv2.w),
                      "+v"(hv3.x), "+v"(hv3.y), "+v"(hv3.z), "+v"(hv3.w),
                      "+v"(xv_next));
    float4 a0 = {0, 0, 0, 0}, a1 = {0, 0, 0, 0};
    fma4(a0, u[0][0], hv0); fma4(a0, u[0][1], hv1);
    fma4(a0, u[0][2], hv2); fma4(a0, u[0][3], hv3);
    fma4(a1, u[1][0], hv0); fma4(a1, u[1][1], hv1);
    fma4(a1, u[1][2], hv2); fma4(a1, u[1][3], hv3);
    float s0 = hsum(a0), s1 = hsum(a1);
    s0 = dpp_add<0xB1>(s0); s0 = dpp_add<0x4E>(s0); s0 = dpp_add<0x141>(s0);
    s1 = dpp_add<0xB1>(s1); s1 = dpp_add<0x4E>(s1); s1 = dpp_add<0x141>(s1);
    const float own = (j & 1) ? s1 : s0;
    const float val = fast_tanh(own + xv_cur);
    if (j < 2) {
      dst[hoff] = val;                      // ds_write: next h state
    } else if ((j & 6) == 4) {              // j == 4,5
      obuf[tc * RNN_H + r_own] = val;       // ds_write: staged output
    }
    barrier_lgkm();                         // no vmcnt drain (R17, proven)
    xv_cur = xv_next;
  };

  for (int c = 0; c < NCH; ++c) {
    // Phase A: commit prefetched chunk c to LDS; issue prefetch of c+1
    // (stays in flight across the lgkm-only barriers below); flush c-1.
    xb4[tid] = p0; xb4[tid + 512] = p1;
    if (c + 1 < NCH) {
      const float4* nx = xw4 + (long)(c + 1) * 1024;
      p0 = nx[tid]; p1 = nx[tid + 512];
    }
    if (c > 0) {
      out4[(long)(c - 1) * 1024 + tid]       = ob4[tid];
      out4[(long)(c - 1) * 1024 + tid + 512] = ob4[tid + 512];
    }
    barrier_lgkm();

    // Phase B: 32 steps, LDS-only traffic, compile-time h ping-pong.
    xv_cur = xbuf[r_own];  // tc = 0 of this chunk
    for (int tc = 0; tc < CH; tc += 2) {
      step(hbuf0, hbuf1, tc);
      step(hbuf1, hbuf0, tc + 1);
    }
  }

  // Final chunk flush + h_last (last step's barrier makes data visible)
  out4[(long)(NCH - 1) * 1024 + tid]       = ob4[tid];
  out4[(long)(NCH - 1) * 1024 + tid + 512] = ob4[tid + 512];
  if (tid < RNN_H)
    hlast[b * RNN_H + tid] = hbuf0[(tid >> 4) * 20 + (tid & 15)];
}

extern "C" void kernel_launch(void* const* d_in, const int* in_sizes, int n_in,
                              void* d_out, int out_size, void* d_ws, size_t ws_size,
                              hipStream_t stream) {
  const float* x    = (const float*)d_in[0];
  const float* h0   = (const float*)d_in[1];
  const float* W    = (const float*)d_in[2];
  const float* U    = (const float*)d_in[3];
  const float* b_ih = (const float*)d_in[4];
  const float* b_hh = (const float*)d_in[5];

  float* out   = (float*)d_out;                           // [B,T,H]
  float* hlast = out + (long)RNN_B * RNN_T * RNN_H;       // [B,H]

  // Stage 1: xw into the output region (read-before-write in scan, per chunk)
  rnn_xw_gemm<<<(RNN_B * RNN_T) / 64, 256, 0, stream>>>(x, W, b_ih, b_hh, out);
  // Stage 2: sequential recurrence, one block per batch element
  rnn_scan<<<RNN_B, 512, 0, stream>>>(out, out, hlast, h0, U);
}